// Round 9
// baseline (317.840 us; speedup 1.0000x reference)
//
#include <hip/hip_runtime.h>

#define N_NODES 50000
#define N_EDGES 300000
#define IN_CH 256
#define HID 512
#define SCAN_NBLK ((N_NODES + 255) / 256)   // 196

typedef __bf16 bf16;
typedef bf16 bf16x8 __attribute__((ext_vector_type(8)));
typedef bf16 bf16x4 __attribute__((ext_vector_type(4)));
typedef float f32x4 __attribute__((ext_vector_type(4)));

__device__ __forceinline__ void load_lds16(const void* g, void* l) {
    __builtin_amdgcn_global_load_lds(
        (const __attribute__((address_space(1))) unsigned int*)g,
        (__attribute__((address_space(3))) unsigned int*)l, 16, 0, 0);
}

// ---------- index dtype detection (int32 vs int64), parallel ----------
__global__ void detect_idx64_par(const unsigned int* __restrict__ ei, int* __restrict__ flag) {
    int stride = gridDim.x * blockDim.x;
    int i = blockIdx.x * blockDim.x + threadIdx.x;
    int local = 0;
    for (int idx = 1 + 2 * i; idx < 2 * N_EDGES; idx += 2 * stride)
        local |= (ei[idx] != 0u);
    if (__any(local)) {
        if ((threadIdx.x & 63) == 0) atomicAnd(flag, 0);
    }
}

__device__ __forceinline__ int load_idx(const void* ei, int i, int is64) {
    if (is64) return (int)((const long long*)ei)[i];
    return ((const int*)ei)[i];
}

// ---------- init (deg=1 self-loop, histogram+cursor=0, flag=1) ----------
__global__ void init_arrays(float* __restrict__ deg, int* __restrict__ counts,
                            int* __restrict__ cursor, int* __restrict__ flag) {
    int i = blockIdx.x * blockDim.x + threadIdx.x;
    if (i == 0) *flag = 1;
    if (i < N_NODES) { deg[i] = 1.0f; counts[i] = 0; cursor[i] = 0; }
}

__global__ void deg_hist(const void* __restrict__ ei, const float* __restrict__ ew,
                         float* __restrict__ deg, int* __restrict__ counts,
                         const int* __restrict__ flag) {
    int e = blockIdx.x * blockDim.x + threadIdx.x;
    if (e >= N_EDGES) return;
    int is64 = *flag;
    int d = load_idx(ei, N_EDGES + e, is64);
    atomicAdd(&deg[d], ew[e]);
    atomicAdd(&counts[d], 1);
}

// ---------- parallel scan, phase A: block-local scan + dis (fused) ----------
__global__ __launch_bounds__(256) void scan_partial(
    const int* __restrict__ counts, const float* __restrict__ deg,
    float* __restrict__ dis, int* __restrict__ row_ptr, int* __restrict__ partials)
{
    __shared__ int psum[256];
    int t = threadIdx.x;
    int i = blockIdx.x * 256 + t;
    if (i < N_NODES) {
        float dg = deg[i];
        dis[i] = (dg > 0.f) ? (1.0f / sqrtf(dg)) : 0.f;
    }
    int c = (i < N_NODES) ? counts[i] : 0;
    psum[t] = c;
    __syncthreads();
#pragma unroll
    for (int off = 1; off < 256; off <<= 1) {
        int v = (t >= off) ? psum[t - off] : 0;
        __syncthreads();
        psum[t] += v;
        __syncthreads();
    }
    if (i < N_NODES) row_ptr[i] = psum[t] - c;
    if (t == 255) partials[blockIdx.x] = psum[255];
}

// ---------- phase B: scan the 196 block totals ----------
__global__ __launch_bounds__(256) void scan_partials(int* __restrict__ partials,
                                                     int* __restrict__ row_ptr) {
    __shared__ int psum[256];
    int t = threadIdx.x;
    int p = (t < SCAN_NBLK) ? partials[t] : 0;
    psum[t] = p;
    __syncthreads();
#pragma unroll
    for (int off = 1; off < 256; off <<= 1) {
        int v = (t >= off) ? psum[t - off] : 0;
        __syncthreads();
        psum[t] += v;
        __syncthreads();
    }
    if (t < SCAN_NBLK) partials[t] = psum[t] - p;
    if (t == 255) row_ptr[N_NODES] = psum[255];
}

// ---------- phase C: add block offsets ----------
__global__ void scan_add(int* __restrict__ row_ptr, const int* __restrict__ partials) {
    int i = blockIdx.x * 256 + threadIdx.x;
    if (i < N_NODES) row_ptr[i] += partials[blockIdx.x];
}

__global__ void fill_csr(const void* __restrict__ ei, const float* __restrict__ ew,
                         const float* __restrict__ dis, const int* __restrict__ row_ptr,
                         int* __restrict__ cursor, int* __restrict__ srcs,
                         float* __restrict__ coefs, const int* __restrict__ flag) {
    int e = blockIdx.x * blockDim.x + threadIdx.x;
    if (e >= N_EDGES) return;
    int is64 = *flag;
    int s = load_idx(ei, e, is64);
    int d = load_idx(ei, N_EDGES + e, is64);
    float coef = dis[s] * ew[e] * dis[d];
    int pos = row_ptr[d] + atomicAdd(&cursor[d], 1);
    srcs[pos] = s;
    coefs[pos] = coef;
}

// ---------- f32 -> bf16: weights (scalar, small) ----------
__global__ void f2b2_kernel(const float* __restrict__ a, bf16* __restrict__ da, int na,
                            const float* __restrict__ b, bf16* __restrict__ db, int nb) {
    int i = blockIdx.x * blockDim.x + threadIdx.x;
    if (i < na) da[i] = (bf16)a[i];
    else if (i - na < nb) db[i - na] = (bf16)b[i - na];
}

// ---------- f32 -> bf16: x feature matrix (vectorized, 8 elems/thread) ----------
__global__ void f2bx_kernel(const float* __restrict__ s, bf16* __restrict__ d) {
    int i = blockIdx.x * blockDim.x + threadIdx.x;    // one per 8 elements
    const int total = N_NODES * IN_CH / 8;
    if (i >= total) return;
    float4 a = ((const float4*)s)[i * 2];
    float4 b = ((const float4*)s)[i * 2 + 1];
    bf16x8 o;
    o[0] = (bf16)a.x; o[1] = (bf16)a.y; o[2] = (bf16)a.z; o[3] = (bf16)a.w;
    o[4] = (bf16)b.x; o[5] = (bf16)b.y; o[6] = (bf16)b.z; o[7] = (bf16)b.w;
    *(bf16x8*)(d + (size_t)i * 8) = o;
}

// ---------- gather aggregation, bf16 rows, C=256 (layer 1), 4-deep unroll ----------
__global__ __launch_bounds__(256) void gather_agg_c256(
    const bf16* __restrict__ xb, const float* __restrict__ dis,
    const int* __restrict__ row_ptr, const int* __restrict__ srcs,
    const float* __restrict__ coefs, bf16* __restrict__ agg)
{
    int wid = threadIdx.x >> 6;
    int lane = threadIdx.x & 63;
    int node = blockIdx.x * 4 + wid;
    if (node >= N_NODES) return;

    float s = dis[node];
    s = s * s;
    float acc[4];
    bf16x4 t0 = *(const bf16x4*)(xb + (size_t)node * IN_CH + lane * 4);
#pragma unroll
    for (int i = 0; i < 4; ++i) acc[i] = s * (float)t0[i];

    int beg = row_ptr[node], end = row_ptr[node + 1];
    int j = beg;
    for (; j + 4 <= end; j += 4) {
        int s0 = srcs[j], s1 = srcs[j + 1], s2 = srcs[j + 2], s3 = srcs[j + 3];
        float c0 = coefs[j], c1 = coefs[j + 1], c2 = coefs[j + 2], c3 = coefs[j + 3];
        bf16x4 r0 = *(const bf16x4*)(xb + (size_t)s0 * IN_CH + lane * 4);
        bf16x4 r1 = *(const bf16x4*)(xb + (size_t)s1 * IN_CH + lane * 4);
        bf16x4 r2 = *(const bf16x4*)(xb + (size_t)s2 * IN_CH + lane * 4);
        bf16x4 r3 = *(const bf16x4*)(xb + (size_t)s3 * IN_CH + lane * 4);
#pragma unroll
        for (int i = 0; i < 4; ++i)
            acc[i] += c0 * (float)r0[i] + c1 * (float)r1[i] + c2 * (float)r2[i] + c3 * (float)r3[i];
    }
    for (; j < end; ++j) {
        int s0 = srcs[j];
        float c0 = coefs[j];
        bf16x4 r0 = *(const bf16x4*)(xb + (size_t)s0 * IN_CH + lane * 4);
#pragma unroll
        for (int i = 0; i < 4; ++i) acc[i] += c0 * (float)r0[i];
    }
    bf16x4 o;
#pragma unroll
    for (int i = 0; i < 4; ++i) o[i] = (bf16)acc[i];
    *(bf16x4*)(agg + (size_t)node * IN_CH + lane * 4) = o;
}

// ---------- gather aggregation, bf16 rows, C=512 (layer 2), 4-deep unroll ----------
__global__ __launch_bounds__(256) void gather_agg_c512(
    const bf16* __restrict__ p, const float* __restrict__ dis,
    const int* __restrict__ row_ptr, const int* __restrict__ srcs,
    const float* __restrict__ coefs, bf16* __restrict__ agg)
{
    int wid = threadIdx.x >> 6;
    int lane = threadIdx.x & 63;
    int node = blockIdx.x * 4 + wid;
    if (node >= N_NODES) return;

    float s = dis[node];
    s = s * s;
    float acc[8];
    bf16x8 t0 = *(const bf16x8*)(p + (size_t)node * HID + lane * 8);
#pragma unroll
    for (int i = 0; i < 8; ++i) acc[i] = s * (float)t0[i];

    int beg = row_ptr[node], end = row_ptr[node + 1];
    int j = beg;
    for (; j + 4 <= end; j += 4) {
        int s0 = srcs[j], s1 = srcs[j + 1], s2 = srcs[j + 2], s3 = srcs[j + 3];
        float c0 = coefs[j], c1 = coefs[j + 1], c2 = coefs[j + 2], c3 = coefs[j + 3];
        bf16x8 r0 = *(const bf16x8*)(p + (size_t)s0 * HID + lane * 8);
        bf16x8 r1 = *(const bf16x8*)(p + (size_t)s1 * HID + lane * 8);
        bf16x8 r2 = *(const bf16x8*)(p + (size_t)s2 * HID + lane * 8);
        bf16x8 r3 = *(const bf16x8*)(p + (size_t)s3 * HID + lane * 8);
#pragma unroll
        for (int i = 0; i < 8; ++i)
            acc[i] += c0 * (float)r0[i] + c1 * (float)r1[i] + c2 * (float)r2[i] + c3 * (float)r3[i];
    }
    for (; j < end; ++j) {
        int s0 = srcs[j];
        float c0 = coefs[j];
        bf16x8 r0 = *(const bf16x8*)(p + (size_t)s0 * HID + lane * 8);
#pragma unroll
        for (int i = 0; i < 8; ++i) acc[i] += c0 * (float)r0[i];
    }
    bf16x8 o;
#pragma unroll
    for (int i = 0; i < 8; ++i) o[i] = (bf16)acc[i];
    *(bf16x8*)(agg + (size_t)node * HID + lane * 8) = o;
}

// ---------- barrier-free MFMA GEMM: full B-panel (128 cols x K) in LDS ----------
// 512 threads, 8 waves (4 row-strips x 2 col-strips), per-wave 32x64 output.
// B staged ONCE (gload_lds, XOR-seg swizzle via inverse-permuted source); one
// barrier; then K-loop has NO syncs: A fragments straight from global (L2/L3-
// resident agg), B from LDS. acc 2x4 f32x4.
template <int K, bool PRELU, bool OUT_BF16>
__global__ __launch_bounds__(512) void gemm_blds(
    const bf16* __restrict__ X, const bf16* __restrict__ Wt,
    const float* __restrict__ bias, const float* __restrict__ prelu_a,
    void* __restrict__ outv, int n)
{
    constexpr int NSEG = K / 8;                 // 16B segments per B row
    extern __shared__ __align__(16) bf16 Bs[];  // 128 * K bf16
    const int tid = threadIdx.x;
    const int lane = tid & 63;
    const int wid = tid >> 6;                   // 0..7
    const int wr = wid >> 1;                    // 0..3 -> 32-row strip
    const int wc = wid & 1;                     // 0..1 -> 64-col strip

    // bijective chunked XCD swizzle (T1)
    const int nwg = gridDim.x;
    const int q = nwg >> 3, r8 = nwg & 7;
    int xcd = blockIdx.x & 7, slot = blockIdx.x >> 3;
    int newid = (xcd < r8 ? xcd * (q + 1) : r8 * (q + 1) + (xcd - r8) * q) + slot;
    const int row0 = (newid >> 2) * 128;        // col-fast within chunk
    const int col0 = (newid & 3) * 128;

    // ---- stage whole B panel, swizzled: LDS slot (r, s) <- global seg s^(r&7) ----
    for (int sl = tid; sl < 128 * NSEG; sl += 512) {
        int r = sl / NSEG;
        int s_lds = sl & (NSEG - 1);
        int s_g = s_lds ^ (r & 7);
        load_lds16(Wt + (size_t)(col0 + r) * K + s_g * 8, &Bs[(size_t)sl * 8]);
    }
    __syncthreads();   // only barrier in the kernel (drains vmcnt)

    // A fragment base pointers (per-lane, clamped)
    const bf16* pA[2];
#pragma unroll
    for (int m = 0; m < 2; ++m) {
        int ra = row0 + wr * 32 + m * 16 + (lane & 15);
        if (ra >= n) ra = n - 1;
        pA[m] = X + (size_t)ra * K + ((lane >> 4) << 3);
    }

    f32x4 acc[2][4] = {};

#pragma unroll 4
    for (int k0 = 0; k0 < K; k0 += 32) {
        bf16x8 af[2], bfr[4];
#pragma unroll
        for (int m = 0; m < 2; ++m)
            af[m] = *(const bf16x8*)(pA[m] + k0);
        int ks = (k0 >> 3) + (lane >> 4);       // global 16B-seg index
#pragma unroll
        for (int nn = 0; nn < 4; ++nn) {
            int r = wc * 64 + nn * 16 + (lane & 15);
            int s_lds = ks ^ (r & 7);
            bfr[nn] = *(const bf16x8*)&Bs[((size_t)r * NSEG + s_lds) * 8];
        }
#pragma unroll
        for (int m = 0; m < 2; ++m)
#pragma unroll
            for (int nn = 0; nn < 4; ++nn)
                acc[m][nn] = __builtin_amdgcn_mfma_f32_16x16x32_bf16(
                    af[m], bfr[nn], acc[m][nn], 0, 0, 0);
    }

    const float ap = PRELU ? *prelu_a : 0.f;
#pragma unroll
    for (int m = 0; m < 2; ++m) {
        int gr_base = row0 + wr * 32 + m * 16 + (lane >> 4) * 4;
#pragma unroll
        for (int nn = 0; nn < 4; ++nn) {
            int gc = col0 + wc * 64 + nn * 16 + (lane & 15);
            float bv = bias[gc];
#pragma unroll
            for (int j = 0; j < 4; ++j) {
                int gr = gr_base + j;
                if (gr < n) {
                    float v = acc[m][nn][j] + bv;
                    if (PRELU) v = (v >= 0.f) ? v : ap * v;
                    if (OUT_BF16) ((bf16*)outv)[(size_t)gr * HID + gc] = (bf16)v;
                    else         ((float*)outv)[(size_t)gr * HID + gc] = v;
                }
            }
        }
    }
}

extern "C" void kernel_launch(void* const* d_in, const int* in_sizes, int n_in,
                              void* d_out, int out_size, void* d_ws, size_t ws_size,
                              hipStream_t stream) {
    const float* x  = (const float*)d_in[0];
    const void*  ei = d_in[1];
    const float* ew = (const float*)d_in[2];
    const float* W1 = (const float*)d_in[3];
    const float* b1 = (const float*)d_in[4];
    const float* W2 = (const float*)d_in[5];
    const float* b2 = (const float*)d_in[6];
    const float* pa = (const float*)d_in[7];

    char* base = (char*)d_ws;
    bf16*  aggb     = (bf16*)base;                          // 51.2 MB
    bf16*  xb       = (bf16*)(base + (size_t)N_NODES * HID * 2);   // 25.6 MB
    bf16*  W1b      = xb + (size_t)N_NODES * IN_CH;
    bf16*  W2b      = W1b + HID * IN_CH;
    float* deg      = (float*)(W2b + HID * HID);
    float* dis      = deg + N_NODES;
    int*   flag     = (int*)(dis + N_NODES);
    int*   counts   = flag + 1;
    int*   cursor   = counts + N_NODES;
    int*   row_ptr  = cursor + N_NODES;                     // N_NODES+1
    int*   srcs     = row_ptr + N_NODES + 1;                // N_EDGES
    float* coefs    = (float*)(srcs + N_EDGES);             // N_EDGES
    int*   partials = (int*)(coefs + N_EDGES);              // SCAN_NBLK

    bf16* p_bf = (bf16*)d_out;   // layer-1 bf16 output lives in d_out, consumed before GEMM2 writes f32

    const int NB = SCAN_NBLK;
    const int EB = (N_EDGES + 255) / 256;
    const int GEMM_NWG = (HID / 128) * ((N_NODES + 127) / 128);   // 4 * 391 = 1564

    // ----- CSR build (once, reused by both layers) -----
    init_arrays<<<NB, 256, 0, stream>>>(deg, counts, cursor, flag);
    detect_idx64_par<<<512, 256, 0, stream>>>((const unsigned int*)ei, flag);
    deg_hist<<<EB, 256, 0, stream>>>(ei, ew, deg, counts, flag);
    scan_partial<<<NB, 256, 0, stream>>>(counts, deg, dis, row_ptr, partials);
    scan_partials<<<1, 256, 0, stream>>>(partials, row_ptr);
    scan_add<<<NB, 256, 0, stream>>>(row_ptr, partials);
    fill_csr<<<EB, 256, 0, stream>>>(ei, ew, dis, row_ptr, cursor, srcs, coefs, flag);

    // ----- dtype conversions (weights scalar; x vectorized) -----
    f2b2_kernel<<<(HID * IN_CH + HID * HID + 255) / 256, 256, 0, stream>>>(
        W1, W1b, HID * IN_CH, W2, W2b, HID * HID);
    f2bx_kernel<<<(N_NODES * IN_CH / 8 + 255) / 256, 256, 0, stream>>>(x, xb);

    // ----- layer 1: gather bf16 x -> barrier-free GEMM + bias + PReLU -> bf16 p -----
    gather_agg_c256<<<(N_NODES + 3) / 4, 256, 0, stream>>>(xb, dis, row_ptr, srcs, coefs, aggb);
    gemm_blds<IN_CH, true, true><<<GEMM_NWG, 512, 128 * IN_CH * sizeof(bf16), stream>>>(
        aggb, W1b, b1, pa, p_bf, N_NODES);

    // ----- layer 2: gather bf16 p -> barrier-free GEMM + bias -> f32 d_out -----
    gather_agg_c512<<<(N_NODES + 3) / 4, 256, 0, stream>>>(p_bf, dis, row_ptr, srcs, coefs, aggb);
    gemm_blds<HID, false, false><<<GEMM_NWG, 512, 128 * HID * sizeof(bf16), stream>>>(
        aggb, W2b, b2, pa, (float*)d_out, N_NODES);
}

// Round 10
// 278.373 us; speedup vs baseline: 1.1418x; 1.1418x over previous
//
#include <hip/hip_runtime.h>

#define N_NODES 50000
#define N_EDGES 300000
#define IN_CH 256
#define HID 512
#define SCAN_NBLK ((N_NODES + 255) / 256)   // 196

typedef __bf16 bf16;
typedef bf16 bf16x8 __attribute__((ext_vector_type(8)));
typedef bf16 bf16x4 __attribute__((ext_vector_type(4)));
typedef float f32x4 __attribute__((ext_vector_type(4)));

__device__ __forceinline__ void load_lds16(const void* g, void* l) {
    __builtin_amdgcn_global_load_lds(
        (const __attribute__((address_space(1))) unsigned int*)g,
        (__attribute__((address_space(3))) unsigned int*)l, 16, 0, 0);
}

// ---------- index dtype detection (int32 vs int64), parallel ----------
__global__ void detect_idx64_par(const unsigned int* __restrict__ ei, int* __restrict__ flag) {
    int stride = gridDim.x * blockDim.x;
    int i = blockIdx.x * blockDim.x + threadIdx.x;
    int local = 0;
    for (int idx = 1 + 2 * i; idx < 2 * N_EDGES; idx += 2 * stride)
        local |= (ei[idx] != 0u);
    if (__any(local)) {
        if ((threadIdx.x & 63) == 0) atomicAnd(flag, 0);
    }
}

__device__ __forceinline__ int load_idx(const void* ei, int i, int is64) {
    if (is64) return (int)((const long long*)ei)[i];
    return ((const int*)ei)[i];
}

// ---------- init (deg=1 self-loop, histogram+cursor=0, flag=1) ----------
__global__ void init_arrays(float* __restrict__ deg, int* __restrict__ counts,
                            int* __restrict__ cursor, int* __restrict__ flag) {
    int i = blockIdx.x * blockDim.x + threadIdx.x;
    if (i == 0) *flag = 1;
    if (i < N_NODES) { deg[i] = 1.0f; counts[i] = 0; cursor[i] = 0; }
}

__global__ void deg_hist(const void* __restrict__ ei, const float* __restrict__ ew,
                         float* __restrict__ deg, int* __restrict__ counts,
                         const int* __restrict__ flag) {
    int e = blockIdx.x * blockDim.x + threadIdx.x;
    if (e >= N_EDGES) return;
    int is64 = *flag;
    int d = load_idx(ei, N_EDGES + e, is64);
    atomicAdd(&deg[d], ew[e]);
    atomicAdd(&counts[d], 1);
}

// ---------- parallel scan, phase A: block-local scan + dis (fused) ----------
__global__ __launch_bounds__(256) void scan_partial(
    const int* __restrict__ counts, const float* __restrict__ deg,
    float* __restrict__ dis, int* __restrict__ row_ptr, int* __restrict__ partials)
{
    __shared__ int psum[256];
    int t = threadIdx.x;
    int i = blockIdx.x * 256 + t;
    if (i < N_NODES) {
        float dg = deg[i];
        dis[i] = (dg > 0.f) ? (1.0f / sqrtf(dg)) : 0.f;
    }
    int c = (i < N_NODES) ? counts[i] : 0;
    psum[t] = c;
    __syncthreads();
#pragma unroll
    for (int off = 1; off < 256; off <<= 1) {
        int v = (t >= off) ? psum[t - off] : 0;
        __syncthreads();
        psum[t] += v;
        __syncthreads();
    }
    if (i < N_NODES) row_ptr[i] = psum[t] - c;
    if (t == 255) partials[blockIdx.x] = psum[255];
}

// ---------- phase B: scan the 196 block totals ----------
__global__ __launch_bounds__(256) void scan_partials(int* __restrict__ partials,
                                                     int* __restrict__ row_ptr) {
    __shared__ int psum[256];
    int t = threadIdx.x;
    int p = (t < SCAN_NBLK) ? partials[t] : 0;
    psum[t] = p;
    __syncthreads();
#pragma unroll
    for (int off = 1; off < 256; off <<= 1) {
        int v = (t >= off) ? psum[t - off] : 0;
        __syncthreads();
        psum[t] += v;
        __syncthreads();
    }
    if (t < SCAN_NBLK) partials[t] = psum[t] - p;
    if (t == 255) row_ptr[N_NODES] = psum[255];
}

// ---------- phase C: add block offsets ----------
__global__ void scan_add(int* __restrict__ row_ptr, const int* __restrict__ partials) {
    int i = blockIdx.x * 256 + threadIdx.x;
    if (i < N_NODES) row_ptr[i] += partials[blockIdx.x];
}

__global__ void fill_csr(const void* __restrict__ ei, const float* __restrict__ ew,
                         const float* __restrict__ dis, const int* __restrict__ row_ptr,
                         int* __restrict__ cursor, int* __restrict__ srcs,
                         float* __restrict__ coefs, const int* __restrict__ flag) {
    int e = blockIdx.x * blockDim.x + threadIdx.x;
    if (e >= N_EDGES) return;
    int is64 = *flag;
    int s = load_idx(ei, e, is64);
    int d = load_idx(ei, N_EDGES + e, is64);
    float coef = dis[s] * ew[e] * dis[d];
    int pos = row_ptr[d] + atomicAdd(&cursor[d], 1);
    srcs[pos] = s;
    coefs[pos] = coef;
}

// ---------- f32 -> bf16: weights (scalar, small) ----------
__global__ void f2b2_kernel(const float* __restrict__ a, bf16* __restrict__ da, int na,
                            const float* __restrict__ b, bf16* __restrict__ db, int nb) {
    int i = blockIdx.x * blockDim.x + threadIdx.x;
    if (i < na) da[i] = (bf16)a[i];
    else if (i - na < nb) db[i - na] = (bf16)b[i - na];
}

// ---------- f32 -> bf16: x feature matrix (vectorized, 8 elems/thread) ----------
__global__ void f2bx_kernel(const float* __restrict__ s, bf16* __restrict__ d) {
    int i = blockIdx.x * blockDim.x + threadIdx.x;    // one per 8 elements
    const int total = N_NODES * IN_CH / 8;
    if (i >= total) return;
    float4 a = ((const float4*)s)[i * 2];
    float4 b = ((const float4*)s)[i * 2 + 1];
    bf16x8 o;
    o[0] = (bf16)a.x; o[1] = (bf16)a.y; o[2] = (bf16)a.z; o[3] = (bf16)a.w;
    o[4] = (bf16)b.x; o[5] = (bf16)b.y; o[6] = (bf16)b.z; o[7] = (bf16)b.w;
    *(bf16x8*)(d + (size_t)i * 8) = o;
}

// ---------- gather aggregation, bf16 rows, C=256 (layer 1), 4-deep unroll ----------
__global__ __launch_bounds__(256) void gather_agg_c256(
    const bf16* __restrict__ xb, const float* __restrict__ dis,
    const int* __restrict__ row_ptr, const int* __restrict__ srcs,
    const float* __restrict__ coefs, bf16* __restrict__ agg)
{
    int wid = threadIdx.x >> 6;
    int lane = threadIdx.x & 63;
    int node = blockIdx.x * 4 + wid;
    if (node >= N_NODES) return;

    float s = dis[node];
    s = s * s;
    float acc[4];
    bf16x4 t0 = *(const bf16x4*)(xb + (size_t)node * IN_CH + lane * 4);
#pragma unroll
    for (int i = 0; i < 4; ++i) acc[i] = s * (float)t0[i];

    int beg = row_ptr[node], end = row_ptr[node + 1];
    int j = beg;
    for (; j + 4 <= end; j += 4) {
        int s0 = srcs[j], s1 = srcs[j + 1], s2 = srcs[j + 2], s3 = srcs[j + 3];
        float c0 = coefs[j], c1 = coefs[j + 1], c2 = coefs[j + 2], c3 = coefs[j + 3];
        bf16x4 r0 = *(const bf16x4*)(xb + (size_t)s0 * IN_CH + lane * 4);
        bf16x4 r1 = *(const bf16x4*)(xb + (size_t)s1 * IN_CH + lane * 4);
        bf16x4 r2 = *(const bf16x4*)(xb + (size_t)s2 * IN_CH + lane * 4);
        bf16x4 r3 = *(const bf16x4*)(xb + (size_t)s3 * IN_CH + lane * 4);
#pragma unroll
        for (int i = 0; i < 4; ++i)
            acc[i] += c0 * (float)r0[i] + c1 * (float)r1[i] + c2 * (float)r2[i] + c3 * (float)r3[i];
    }
    for (; j < end; ++j) {
        int s0 = srcs[j];
        float c0 = coefs[j];
        bf16x4 r0 = *(const bf16x4*)(xb + (size_t)s0 * IN_CH + lane * 4);
#pragma unroll
        for (int i = 0; i < 4; ++i) acc[i] += c0 * (float)r0[i];
    }
    bf16x4 o;
#pragma unroll
    for (int i = 0; i < 4; ++i) o[i] = (bf16)acc[i];
    *(bf16x4*)(agg + (size_t)node * IN_CH + lane * 4) = o;
}

// ---------- gather aggregation, bf16 rows, C=512 (layer 2), 4-deep unroll ----------
__global__ __launch_bounds__(256) void gather_agg_c512(
    const bf16* __restrict__ p, const float* __restrict__ dis,
    const int* __restrict__ row_ptr, const int* __restrict__ srcs,
    const float* __restrict__ coefs, bf16* __restrict__ agg)
{
    int wid = threadIdx.x >> 6;
    int lane = threadIdx.x & 63;
    int node = blockIdx.x * 4 + wid;
    if (node >= N_NODES) return;

    float s = dis[node];
    s = s * s;
    float acc[8];
    bf16x8 t0 = *(const bf16x8*)(p + (size_t)node * HID + lane * 8);
#pragma unroll
    for (int i = 0; i < 8; ++i) acc[i] = s * (float)t0[i];

    int beg = row_ptr[node], end = row_ptr[node + 1];
    int j = beg;
    for (; j + 4 <= end; j += 4) {
        int s0 = srcs[j], s1 = srcs[j + 1], s2 = srcs[j + 2], s3 = srcs[j + 3];
        float c0 = coefs[j], c1 = coefs[j + 1], c2 = coefs[j + 2], c3 = coefs[j + 3];
        bf16x8 r0 = *(const bf16x8*)(p + (size_t)s0 * HID + lane * 8);
        bf16x8 r1 = *(const bf16x8*)(p + (size_t)s1 * HID + lane * 8);
        bf16x8 r2 = *(const bf16x8*)(p + (size_t)s2 * HID + lane * 8);
        bf16x8 r3 = *(const bf16x8*)(p + (size_t)s3 * HID + lane * 8);
#pragma unroll
        for (int i = 0; i < 8; ++i)
            acc[i] += c0 * (float)r0[i] + c1 * (float)r1[i] + c2 * (float)r2[i] + c3 * (float)r3[i];
    }
    for (; j < end; ++j) {
        int s0 = srcs[j];
        float c0 = coefs[j];
        bf16x8 r0 = *(const bf16x8*)(p + (size_t)s0 * HID + lane * 8);
#pragma unroll
        for (int i = 0; i < 8; ++i) acc[i] += c0 * (float)r0[i];
    }
    bf16x8 o;
#pragma unroll
    for (int i = 0; i < 8; ++i) o[i] = (bf16)acc[i];
    *(bf16x8*)(agg + (size_t)node * HID + lane * 8) = o;
}

// ---------- MFMA bf16 GEMM: out[n,512] = X[n,K] @ Wt[512,K]^T + bias ----------
// 128x128 tile, BK=32, 4 waves, T1 XCD swizzle. Double-buffered LDS with
// COUNTED vmcnt (T3/T4-min): STAGE(t+1) issued before compute(t); barriers are
// raw s_barrier (no vmcnt(0) drain); prefetch loads stay in flight across them.
template <int K, bool PRELU, bool OUT_BF16>
__global__ __launch_bounds__(256) void gemm_mfma(
    const bf16* __restrict__ X, const bf16* __restrict__ Wt,
    const float* __restrict__ bias, const float* __restrict__ prelu_a,
    void* __restrict__ outv, int n)
{
    constexpr int T = K / 32;
    __shared__ __align__(16) bf16 As[2][128 * 32];
    __shared__ __align__(16) bf16 Bs[2][128 * 32];
    const int tid = threadIdx.x;
    const int lane = tid & 63;
    const int wid = tid >> 6;
    const int wr = wid >> 1, wc = wid & 1;

    // bijective chunked XCD swizzle (T1)
    const int nwg = gridDim.x;
    const int q = nwg >> 3, r8 = nwg & 7;
    int xcd = blockIdx.x & 7, slot = blockIdx.x >> 3;
    int newid = (xcd < r8 ? xcd * (q + 1) : r8 * (q + 1) + (xcd - r8) * q) + slot;
    const int row0 = (newid >> 2) * 128;   // col-fast: 4 col-blocks adjacent
    const int col0 = (newid & 3) * 128;

    // stage one 128x32 K-tile of A and B into buffer `buf` (4 gload_lds/thread)
    auto STAGE = [&](int buf, int t) {
#pragma unroll
        for (int h = 0; h < 2; ++h) {
            int ss = tid + h * 256;          // 0..511
            int r = ss >> 2;                 // 0..127
            int c = (ss & 3) ^ (r & 3);      // inverse-permuted source seg
            int ra = row0 + r; if (ra >= n) ra = n - 1;
            load_lds16(X + (size_t)ra * K + t * 32 + c * 8, &As[buf][ss * 8]);
            load_lds16(Wt + (size_t)(col0 + r) * K + t * 32 + c * 8, &Bs[buf][ss * 8]);
        }
    };

    f32x4 acc[4][4] = {};
    STAGE(0, 0);

#pragma unroll
    for (int t = 0; t < T; ++t) {
        if (t + 1 < T) {
            STAGE((t + 1) & 1, t + 1);               // prefetch next tile
            asm volatile("s_waitcnt vmcnt(4)");      // wait only CURRENT tile's 4 loads
        } else {
            asm volatile("s_waitcnt vmcnt(0)");      // last tile: drain
        }
        __builtin_amdgcn_s_barrier();                // all waves' cur-tile LDS ready
        __builtin_amdgcn_sched_barrier(0);           // rule #18: pin reads after barrier

        const bf16* Ab = As[t & 1];
        const bf16* Bb = Bs[t & 1];
        bf16x8 af[4], bfr[4];
#pragma unroll
        for (int m = 0; m < 4; ++m) {
            int r = wr * 64 + m * 16 + (lane & 15);
            int seg = r * 4 + ((lane >> 4) ^ (r & 3));
            af[m] = *(const bf16x8*)&Ab[seg * 8];
        }
#pragma unroll
        for (int nn = 0; nn < 4; ++nn) {
            int r = wc * 64 + nn * 16 + (lane & 15);
            int seg = r * 4 + ((lane >> 4) ^ (r & 3));
            bfr[nn] = *(const bf16x8*)&Bb[seg * 8];
        }
#pragma unroll
        for (int m = 0; m < 4; ++m)
#pragma unroll
            for (int nn = 0; nn < 4; ++nn)
                acc[m][nn] = __builtin_amdgcn_mfma_f32_16x16x32_bf16(
                    af[m], bfr[nn], acc[m][nn], 0, 0, 0);

        __builtin_amdgcn_sched_barrier(0);           // keep reads before the release barrier
        __builtin_amdgcn_s_barrier();                // all reads done -> next iter may restage
    }

    const float ap = PRELU ? *prelu_a : 0.f;
#pragma unroll
    for (int m = 0; m < 4; ++m) {
        int gr_base = row0 + wr * 64 + m * 16 + (lane >> 4) * 4;
#pragma unroll
        for (int nn = 0; nn < 4; ++nn) {
            int gc = col0 + wc * 64 + nn * 16 + (lane & 15);
            float bv = bias[gc];
#pragma unroll
            for (int j = 0; j < 4; ++j) {
                int gr = gr_base + j;
                if (gr < n) {
                    float v = acc[m][nn][j] + bv;
                    if (PRELU) v = (v >= 0.f) ? v : ap * v;
                    if (OUT_BF16) ((bf16*)outv)[(size_t)gr * HID + gc] = (bf16)v;
                    else         ((float*)outv)[(size_t)gr * HID + gc] = v;
                }
            }
        }
    }
}

extern "C" void kernel_launch(void* const* d_in, const int* in_sizes, int n_in,
                              void* d_out, int out_size, void* d_ws, size_t ws_size,
                              hipStream_t stream) {
    const float* x  = (const float*)d_in[0];
    const void*  ei = d_in[1];
    const float* ew = (const float*)d_in[2];
    const float* W1 = (const float*)d_in[3];
    const float* b1 = (const float*)d_in[4];
    const float* W2 = (const float*)d_in[5];
    const float* b2 = (const float*)d_in[6];
    const float* pa = (const float*)d_in[7];

    char* base = (char*)d_ws;
    bf16*  aggb     = (bf16*)base;                          // 51.2 MB
    bf16*  xb       = (bf16*)(base + (size_t)N_NODES * HID * 2);   // 25.6 MB
    bf16*  W1b      = xb + (size_t)N_NODES * IN_CH;
    bf16*  W2b      = W1b + HID * IN_CH;
    float* deg      = (float*)(W2b + HID * HID);
    float* dis      = deg + N_NODES;
    int*   flag     = (int*)(dis + N_NODES);
    int*   counts   = flag + 1;
    int*   cursor   = counts + N_NODES;
    int*   row_ptr  = cursor + N_NODES;                     // N_NODES+1
    int*   srcs     = row_ptr + N_NODES + 1;                // N_EDGES
    float* coefs    = (float*)(srcs + N_EDGES);             // N_EDGES
    int*   partials = (int*)(coefs + N_EDGES);              // SCAN_NBLK

    bf16* p_bf = (bf16*)d_out;   // layer-1 bf16 output lives in d_out, consumed before GEMM2 writes f32

    const int NB = SCAN_NBLK;
    const int EB = (N_EDGES + 255) / 256;
    const int GEMM_NWG = (HID / 128) * ((N_NODES + 127) / 128);   // 4 * 391 = 1564

    // ----- CSR build (once, reused by both layers) -----
    init_arrays<<<NB, 256, 0, stream>>>(deg, counts, cursor, flag);
    detect_idx64_par<<<512, 256, 0, stream>>>((const unsigned int*)ei, flag);
    deg_hist<<<EB, 256, 0, stream>>>(ei, ew, deg, counts, flag);
    scan_partial<<<NB, 256, 0, stream>>>(counts, deg, dis, row_ptr, partials);
    scan_partials<<<1, 256, 0, stream>>>(partials, row_ptr);
    scan_add<<<NB, 256, 0, stream>>>(row_ptr, partials);
    fill_csr<<<EB, 256, 0, stream>>>(ei, ew, dis, row_ptr, cursor, srcs, coefs, flag);

    // ----- dtype conversions (weights scalar; x vectorized) -----
    f2b2_kernel<<<(HID * IN_CH + HID * HID + 255) / 256, 256, 0, stream>>>(
        W1, W1b, HID * IN_CH, W2, W2b, HID * HID);
    f2bx_kernel<<<(N_NODES * IN_CH / 8 + 255) / 256, 256, 0, stream>>>(x, xb);

    // ----- layer 1: gather bf16 x -> GEMM + bias + PReLU -> bf16 p (in d_out) -----
    gather_agg_c256<<<(N_NODES + 3) / 4, 256, 0, stream>>>(xb, dis, row_ptr, srcs, coefs, aggb);
    gemm_mfma<IN_CH, true, true><<<GEMM_NWG, 256, 0, stream>>>(
        aggb, W1b, b1, pa, p_bf, N_NODES);

    // ----- layer 2: gather bf16 p -> GEMM + bias -> f32 d_out -----
    gather_agg_c512<<<(N_NODES + 3) / 4, 256, 0, stream>>>(p_bf, dis, row_ptr, srcs, coefs, aggb);
    gemm_mfma<HID, false, false><<<GEMM_NWG, 256, 0, stream>>>(
        aggb, W2b, b2, pa, (float*)d_out, N_NODES);
}

// Round 11
// 263.780 us; speedup vs baseline: 1.2049x; 1.0553x over previous
//
#include <hip/hip_runtime.h>

#define N_NODES 50000
#define N_EDGES 300000
#define IN_CH 256
#define HID 512
#define SCAN_NBLK ((N_NODES + 255) / 256)   // 196

typedef __bf16 bf16;
typedef bf16 bf16x8 __attribute__((ext_vector_type(8)));
typedef bf16 bf16x4 __attribute__((ext_vector_type(4)));
typedef float f32x4 __attribute__((ext_vector_type(4)));

__device__ __forceinline__ void load_lds16(const void* g, void* l) {
    __builtin_amdgcn_global_load_lds(
        (const __attribute__((address_space(1))) unsigned int*)g,
        (__attribute__((address_space(3))) unsigned int*)l, 16, 0, 0);
}

// ---------- index dtype detection (int32 vs int64), parallel ----------
__global__ void detect_idx64_par(const unsigned int* __restrict__ ei, int* __restrict__ flag) {
    int stride = gridDim.x * blockDim.x;
    int i = blockIdx.x * blockDim.x + threadIdx.x;
    int local = 0;
    for (int idx = 1 + 2 * i; idx < 2 * N_EDGES; idx += 2 * stride)
        local |= (ei[idx] != 0u);
    if (__any(local)) {
        if ((threadIdx.x & 63) == 0) atomicAnd(flag, 0);
    }
}

__device__ __forceinline__ int load_idx(const void* ei, int i, int is64) {
    if (is64) return (int)((const long long*)ei)[i];
    return ((const int*)ei)[i];
}

// ---------- init (deg=1 self-loop, histogram+cursor=0, flag=1) ----------
__global__ void init_arrays(float* __restrict__ deg, int* __restrict__ counts,
                            int* __restrict__ cursor, int* __restrict__ flag) {
    int i = blockIdx.x * blockDim.x + threadIdx.x;
    if (i == 0) *flag = 1;
    if (i < N_NODES) { deg[i] = 1.0f; counts[i] = 0; cursor[i] = 0; }
}

__global__ void deg_hist(const void* __restrict__ ei, const float* __restrict__ ew,
                         float* __restrict__ deg, int* __restrict__ counts,
                         const int* __restrict__ flag) {
    int e = blockIdx.x * blockDim.x + threadIdx.x;
    if (e >= N_EDGES) return;
    int is64 = *flag;
    int d = load_idx(ei, N_EDGES + e, is64);
    atomicAdd(&deg[d], ew[e]);
    atomicAdd(&counts[d], 1);
}

// ---------- parallel scan, phase A: block-local scan + dis (fused) ----------
__global__ __launch_bounds__(256) void scan_partial(
    const int* __restrict__ counts, const float* __restrict__ deg,
    float* __restrict__ dis, int* __restrict__ row_ptr, int* __restrict__ partials)
{
    __shared__ int psum[256];
    int t = threadIdx.x;
    int i = blockIdx.x * 256 + t;
    if (i < N_NODES) {
        float dg = deg[i];
        dis[i] = (dg > 0.f) ? (1.0f / sqrtf(dg)) : 0.f;
    }
    int c = (i < N_NODES) ? counts[i] : 0;
    psum[t] = c;
    __syncthreads();
#pragma unroll
    for (int off = 1; off < 256; off <<= 1) {
        int v = (t >= off) ? psum[t - off] : 0;
        __syncthreads();
        psum[t] += v;
        __syncthreads();
    }
    if (i < N_NODES) row_ptr[i] = psum[t] - c;
    if (t == 255) partials[blockIdx.x] = psum[255];
}

// ---------- phase B: scan the 196 block totals ----------
__global__ __launch_bounds__(256) void scan_partials(int* __restrict__ partials,
                                                     int* __restrict__ row_ptr) {
    __shared__ int psum[256];
    int t = threadIdx.x;
    int p = (t < SCAN_NBLK) ? partials[t] : 0;
    psum[t] = p;
    __syncthreads();
#pragma unroll
    for (int off = 1; off < 256; off <<= 1) {
        int v = (t >= off) ? psum[t - off] : 0;
        __syncthreads();
        psum[t] += v;
        __syncthreads();
    }
    if (t < SCAN_NBLK) partials[t] = psum[t] - p;
    if (t == 255) row_ptr[N_NODES] = psum[255];
}

// ---------- phase C: add block offsets ----------
__global__ void scan_add(int* __restrict__ row_ptr, const int* __restrict__ partials) {
    int i = blockIdx.x * 256 + threadIdx.x;
    if (i < N_NODES) row_ptr[i] += partials[blockIdx.x];
}

// ---------- fill CSR with PACKED edges: int2{src, coef_bits} ----------
__global__ void fill_csr(const void* __restrict__ ei, const float* __restrict__ ew,
                         const float* __restrict__ dis, const int* __restrict__ row_ptr,
                         int* __restrict__ cursor, int2* __restrict__ edges,
                         const int* __restrict__ flag) {
    int e = blockIdx.x * blockDim.x + threadIdx.x;
    if (e >= N_EDGES) return;
    int is64 = *flag;
    int s = load_idx(ei, e, is64);
    int d = load_idx(ei, N_EDGES + e, is64);
    float coef = dis[s] * ew[e] * dis[d];
    int pos = row_ptr[d] + atomicAdd(&cursor[d], 1);
    edges[pos] = make_int2(s, __float_as_int(coef));
}

// ---------- f32 -> bf16: x (vectorized, 8/thread) + both weights (scalar tail) ----------
__global__ void f2ball_kernel(const float* __restrict__ x, bf16* __restrict__ xb,
                              const float* __restrict__ W1, bf16* __restrict__ W1b, int n1,
                              const float* __restrict__ W2, bf16* __restrict__ W2b, int n2) {
    const int total_x8 = N_NODES * IN_CH / 8;
    int i = blockIdx.x * blockDim.x + threadIdx.x;
    if (i < total_x8) {
        float4 a = ((const float4*)x)[i * 2];
        float4 b = ((const float4*)x)[i * 2 + 1];
        bf16x8 o;
        o[0] = (bf16)a.x; o[1] = (bf16)a.y; o[2] = (bf16)a.z; o[3] = (bf16)a.w;
        o[4] = (bf16)b.x; o[5] = (bf16)b.y; o[6] = (bf16)b.z; o[7] = (bf16)b.w;
        *(bf16x8*)(xb + (size_t)i * 8) = o;
    } else {
        int j = i - total_x8;
        if (j < n1) W1b[j] = (bf16)W1[j];
        else if (j - n1 < n2) W2b[j - n1] = (bf16)W2[j - n1];
    }
}

// ---------- gather aggregation, bf16 rows, C=256 (layer 1), 4-deep unroll ----------
__global__ __launch_bounds__(256) void gather_agg_c256(
    const bf16* __restrict__ xb, const float* __restrict__ dis,
    const int* __restrict__ row_ptr, const int2* __restrict__ edges,
    bf16* __restrict__ agg)
{
    int wid = threadIdx.x >> 6;
    int lane = threadIdx.x & 63;
    int node = blockIdx.x * 4 + wid;
    if (node >= N_NODES) return;

    float s = dis[node];
    s = s * s;
    float acc[4];
    bf16x4 t0 = *(const bf16x4*)(xb + (size_t)node * IN_CH + lane * 4);
#pragma unroll
    for (int i = 0; i < 4; ++i) acc[i] = s * (float)t0[i];

    int beg = row_ptr[node], end = row_ptr[node + 1];
    int j = beg;
    for (; j + 4 <= end; j += 4) {
        int2 e0 = edges[j], e1 = edges[j + 1], e2 = edges[j + 2], e3 = edges[j + 3];
        float c0 = __int_as_float(e0.y), c1 = __int_as_float(e1.y);
        float c2 = __int_as_float(e2.y), c3 = __int_as_float(e3.y);
        bf16x4 r0 = *(const bf16x4*)(xb + (size_t)e0.x * IN_CH + lane * 4);
        bf16x4 r1 = *(const bf16x4*)(xb + (size_t)e1.x * IN_CH + lane * 4);
        bf16x4 r2 = *(const bf16x4*)(xb + (size_t)e2.x * IN_CH + lane * 4);
        bf16x4 r3 = *(const bf16x4*)(xb + (size_t)e3.x * IN_CH + lane * 4);
#pragma unroll
        for (int i = 0; i < 4; ++i)
            acc[i] += c0 * (float)r0[i] + c1 * (float)r1[i] + c2 * (float)r2[i] + c3 * (float)r3[i];
    }
    for (; j < end; ++j) {
        int2 e0 = edges[j];
        float c0 = __int_as_float(e0.y);
        bf16x4 r0 = *(const bf16x4*)(xb + (size_t)e0.x * IN_CH + lane * 4);
#pragma unroll
        for (int i = 0; i < 4; ++i) acc[i] += c0 * (float)r0[i];
    }
    bf16x4 o;
#pragma unroll
    for (int i = 0; i < 4; ++i) o[i] = (bf16)acc[i];
    *(bf16x4*)(agg + (size_t)node * IN_CH + lane * 4) = o;
}

// ---------- gather aggregation, bf16 rows, C=512 (layer 2), 4-deep unroll ----------
__global__ __launch_bounds__(256) void gather_agg_c512(
    const bf16* __restrict__ p, const float* __restrict__ dis,
    const int* __restrict__ row_ptr, const int2* __restrict__ edges,
    bf16* __restrict__ agg)
{
    int wid = threadIdx.x >> 6;
    int lane = threadIdx.x & 63;
    int node = blockIdx.x * 4 + wid;
    if (node >= N_NODES) return;

    float s = dis[node];
    s = s * s;
    float acc[8];
    bf16x8 t0 = *(const bf16x8*)(p + (size_t)node * HID + lane * 8);
#pragma unroll
    for (int i = 0; i < 8; ++i) acc[i] = s * (float)t0[i];

    int beg = row_ptr[node], end = row_ptr[node + 1];
    int j = beg;
    for (; j + 4 <= end; j += 4) {
        int2 e0 = edges[j], e1 = edges[j + 1], e2 = edges[j + 2], e3 = edges[j + 3];
        float c0 = __int_as_float(e0.y), c1 = __int_as_float(e1.y);
        float c2 = __int_as_float(e2.y), c3 = __int_as_float(e3.y);
        bf16x8 r0 = *(const bf16x8*)(p + (size_t)e0.x * HID + lane * 8);
        bf16x8 r1 = *(const bf16x8*)(p + (size_t)e1.x * HID + lane * 8);
        bf16x8 r2 = *(const bf16x8*)(p + (size_t)e2.x * HID + lane * 8);
        bf16x8 r3 = *(const bf16x8*)(p + (size_t)e3.x * HID + lane * 8);
#pragma unroll
        for (int i = 0; i < 8; ++i)
            acc[i] += c0 * (float)r0[i] + c1 * (float)r1[i] + c2 * (float)r2[i] + c3 * (float)r3[i];
    }
    for (; j < end; ++j) {
        int2 e0 = edges[j];
        float c0 = __int_as_float(e0.y);
        bf16x8 r0 = *(const bf16x8*)(p + (size_t)e0.x * HID + lane * 8);
#pragma unroll
        for (int i = 0; i < 8; ++i) acc[i] += c0 * (float)r0[i];
    }
    bf16x8 o;
#pragma unroll
    for (int i = 0; i < 8; ++i) o[i] = (bf16)acc[i];
    *(bf16x8*)(agg + (size_t)node * HID + lane * 8) = o;
}

// ---------- MFMA bf16 GEMM: out[n,512] = X[n,K] @ Wt[512,K]^T + bias ----------
// 256x128 tile, 8 waves (4 row-strips x 2 col-strips, 64x64 out each), BK=32
// double-buffered with counted vmcnt(3), T1 XCD swizzle, seg-swizzled LDS.
template <int K, bool PRELU, bool OUT_BF16>
__global__ __launch_bounds__(512) void gemm_mfma(
    const bf16* __restrict__ X, const bf16* __restrict__ Wt,
    const float* __restrict__ bias, const float* __restrict__ prelu_a,
    void* __restrict__ outv, int n)
{
    constexpr int T = K / 32;
    __shared__ __align__(16) bf16 As[2][256 * 32];
    __shared__ __align__(16) bf16 Bs[2][128 * 32];
    const int tid = threadIdx.x;
    const int lane = tid & 63;
    const int wid = tid >> 6;              // 0..7
    const int wr = wid >> 1;               // 0..3 -> 64-row strip
    const int wc = wid & 1;                // 0..1 -> 64-col strip

    // bijective chunked XCD swizzle (T1); nwg = 784, 784%8==0
    const int nwg = gridDim.x;
    const int q = nwg >> 3, r8 = nwg & 7;
    int xcd = blockIdx.x & 7, slot = blockIdx.x >> 3;
    int newid = (xcd < r8 ? xcd * (q + 1) : r8 * (q + 1) + (xcd - r8) * q) + slot;
    const int row0 = (newid >> 2) * 256;   // col-fast: 4 col-blocks adjacent
    const int col0 = (newid & 3) * 128;

    // stage one K-tile: A 256x32 (2 segs/thread) + B 128x32 (1 seg/thread)
    auto STAGE = [&](int buf, int t) {
#pragma unroll
        for (int h = 0; h < 2; ++h) {
            int ss = tid + h * 512;          // 0..1023
            int r = ss >> 2;                 // 0..255
            int c = (ss & 3) ^ (r & 3);      // inverse-permuted source seg
            int ra = row0 + r; if (ra >= n) ra = n - 1;
            load_lds16(X + (size_t)ra * K + t * 32 + c * 8, &As[buf][ss * 8]);
        }
        {
            int r = tid >> 2;                // 0..127
            int c = (tid & 3) ^ (r & 3);
            load_lds16(Wt + (size_t)(col0 + r) * K + t * 32 + c * 8, &Bs[buf][tid * 8]);
        }
    };

    f32x4 acc[4][4] = {};
    STAGE(0, 0);

#pragma unroll
    for (int t = 0; t < T; ++t) {
        if (t + 1 < T) {
            STAGE((t + 1) & 1, t + 1);               // prefetch next tile
            asm volatile("s_waitcnt vmcnt(3)");      // wait only CURRENT tile's 3 loads
        } else {
            asm volatile("s_waitcnt vmcnt(0)");      // last tile: drain
        }
        __builtin_amdgcn_s_barrier();
        __builtin_amdgcn_sched_barrier(0);           // rule #18: pin reads after barrier

        const bf16* Ab = As[t & 1];
        const bf16* Bb = Bs[t & 1];
        bf16x8 af[4], bfr[4];
#pragma unroll
        for (int m = 0; m < 4; ++m) {
            int r = wr * 64 + m * 16 + (lane & 15);          // 0..255
            int seg = r * 4 + ((lane >> 4) ^ (r & 3));
            af[m] = *(const bf16x8*)&Ab[seg * 8];
        }
#pragma unroll
        for (int nn = 0; nn < 4; ++nn) {
            int r = wc * 64 + nn * 16 + (lane & 15);         // 0..127
            int seg = r * 4 + ((lane >> 4) ^ (r & 3));
            bfr[nn] = *(const bf16x8*)&Bb[seg * 8];
        }
#pragma unroll
        for (int m = 0; m < 4; ++m)
#pragma unroll
            for (int nn = 0; nn < 4; ++nn)
                acc[m][nn] = __builtin_amdgcn_mfma_f32_16x16x32_bf16(
                    af[m], bfr[nn], acc[m][nn], 0, 0, 0);

        __builtin_amdgcn_sched_barrier(0);           // keep reads before the release barrier
        __builtin_amdgcn_s_barrier();                // all reads done -> next iter may restage
    }

    const float ap = PRELU ? *prelu_a : 0.f;
#pragma unroll
    for (int m = 0; m < 4; ++m) {
        int gr_base = row0 + wr * 64 + m * 16 + (lane >> 4) * 4;
#pragma unroll
        for (int nn = 0; nn < 4; ++nn) {
            int gc = col0 + wc * 64 + nn * 16 + (lane & 15);
            float bv = bias[gc];
#pragma unroll
            for (int j = 0; j < 4; ++j) {
                int gr = gr_base + j;
                if (gr < n) {
                    float v = acc[m][nn][j] + bv;
                    if (PRELU) v = (v >= 0.f) ? v : ap * v;
                    if (OUT_BF16) ((bf16*)outv)[(size_t)gr * HID + gc] = (bf16)v;
                    else         ((float*)outv)[(size_t)gr * HID + gc] = v;
                }
            }
        }
    }
}

extern "C" void kernel_launch(void* const* d_in, const int* in_sizes, int n_in,
                              void* d_out, int out_size, void* d_ws, size_t ws_size,
                              hipStream_t stream) {
    const float* x  = (const float*)d_in[0];
    const void*  ei = d_in[1];
    const float* ew = (const float*)d_in[2];
    const float* W1 = (const float*)d_in[3];
    const float* b1 = (const float*)d_in[4];
    const float* W2 = (const float*)d_in[5];
    const float* b2 = (const float*)d_in[6];
    const float* pa = (const float*)d_in[7];

    char* base = (char*)d_ws;
    bf16*  aggb     = (bf16*)base;                          // 51.2 MB
    bf16*  xb       = (bf16*)(base + (size_t)N_NODES * HID * 2);   // 25.6 MB
    bf16*  W1b      = xb + (size_t)N_NODES * IN_CH;
    bf16*  W2b      = W1b + HID * IN_CH;
    float* deg      = (float*)(W2b + HID * HID);
    float* dis      = deg + N_NODES;
    int*   flag     = (int*)(dis + N_NODES);
    int*   counts   = flag + 1;
    int*   cursor   = counts + N_NODES;
    int*   row_ptr  = cursor + N_NODES;                     // N_NODES+1
    int2*  edges    = (int2*)(row_ptr + N_NODES + 1);       // N_EDGES (8B each)
    int*   partials = (int*)(edges + N_EDGES);              // SCAN_NBLK

    bf16* p_bf = (bf16*)d_out;   // layer-1 bf16 output lives in d_out, consumed before GEMM2 writes f32

    const int NB = SCAN_NBLK;
    const int EB = (N_EDGES + 255) / 256;
    const int GEMM_NWG = (HID / 128) * ((N_NODES + 255) / 256);   // 4 * 196 = 784

    // ----- CSR build (once, reused by both layers) -----
    init_arrays<<<NB, 256, 0, stream>>>(deg, counts, cursor, flag);
    detect_idx64_par<<<512, 256, 0, stream>>>((const unsigned int*)ei, flag);
    deg_hist<<<EB, 256, 0, stream>>>(ei, ew, deg, counts, flag);
    scan_partial<<<NB, 256, 0, stream>>>(counts, deg, dis, row_ptr, partials);
    scan_partials<<<1, 256, 0, stream>>>(partials, row_ptr);
    scan_add<<<NB, 256, 0, stream>>>(row_ptr, partials);
    fill_csr<<<EB, 256, 0, stream>>>(ei, ew, dis, row_ptr, cursor, edges, flag);

    // ----- dtype conversions (one launch: x vectorized + weights scalar) -----
    {
        int total = N_NODES * IN_CH / 8 + HID * IN_CH + HID * HID;
        f2ball_kernel<<<(total + 255) / 256, 256, 0, stream>>>(
            x, xb, W1, W1b, HID * IN_CH, W2, W2b, HID * HID);
    }

    // ----- layer 1: gather bf16 x -> GEMM + bias + PReLU -> bf16 p (in d_out) -----
    gather_agg_c256<<<(N_NODES + 3) / 4, 256, 0, stream>>>(xb, dis, row_ptr, edges, aggb);
    gemm_mfma<IN_CH, true, true><<<GEMM_NWG, 512, 0, stream>>>(
        aggb, W1b, b1, pa, p_bf, N_NODES);

    // ----- layer 2: gather bf16 p -> GEMM + bias -> f32 d_out -----
    gather_agg_c512<<<(N_NODES + 3) / 4, 256, 0, stream>>>(p_bf, dis, row_ptr, edges, aggb);
    gemm_mfma<HID, false, false><<<GEMM_NWG, 512, 0, stream>>>(
        aggb, W2b, b2, pa, (float*)d_out, N_NODES);
}

// Round 12
// 234.784 us; speedup vs baseline: 1.3538x; 1.1235x over previous
//
#include <hip/hip_runtime.h>

#define N_NODES 50000
#define N_EDGES 300000
#define IN_CH 256
#define HID 512
#define SCAN_NBLK ((N_NODES + 255) / 256)   // 196

typedef __bf16 bf16;
typedef bf16 bf16x8 __attribute__((ext_vector_type(8)));
typedef bf16 bf16x4 __attribute__((ext_vector_type(4)));
typedef float f32x4 __attribute__((ext_vector_type(4)));

__device__ __forceinline__ void load_lds16(const void* g, void* l) {
    __builtin_amdgcn_global_load_lds(
        (const __attribute__((address_space(1))) unsigned int*)g,
        (__attribute__((address_space(3))) unsigned int*)l, 16, 0, 0);
}

// ---------- inline index-dtype detection ----------
// int64 little-endian with values < 2^31 => the 8 odd 32-bit words of the
// first 64 B are ALL zero. int32 random indices: P(all 8 == 0) ~ (2e-5)^8.
__device__ __forceinline__ int detect64(const unsigned int* __restrict__ ei) {
    unsigned v = 0;
#pragma unroll
    for (int k = 1; k < 16; k += 2) v |= ei[k];
    return v == 0;
}

__device__ __forceinline__ int load_idx(const void* ei, int i, int is64) {
    if (is64) return (int)((const long long*)ei)[i];
    return ((const int*)ei)[i];
}

// ---------- prep: init node arrays + all f32->bf16 conversions (one launch) ----------
__global__ void prep_kernel(float* __restrict__ deg, int* __restrict__ counts,
                            int* __restrict__ cursor,
                            const float* __restrict__ x, bf16* __restrict__ xb,
                            const float* __restrict__ W1, bf16* __restrict__ W1b, int n1,
                            const float* __restrict__ W2, bf16* __restrict__ W2b, int n2) {
    int i = blockIdx.x * blockDim.x + threadIdx.x;
    if (i < N_NODES) { deg[i] = 1.0f; counts[i] = 0; cursor[i] = 0; }
    const int TX = N_NODES * IN_CH / 8;
    if (i < TX) {
        float4 a = ((const float4*)x)[i * 2];
        float4 b = ((const float4*)x)[i * 2 + 1];
        bf16x8 o;
        o[0] = (bf16)a.x; o[1] = (bf16)a.y; o[2] = (bf16)a.z; o[3] = (bf16)a.w;
        o[4] = (bf16)b.x; o[5] = (bf16)b.y; o[6] = (bf16)b.z; o[7] = (bf16)b.w;
        *(bf16x8*)(xb + (size_t)i * 8) = o;
    } else {
        int j = i - TX;
        if (j < n1) W1b[j] = (bf16)W1[j];
        else if (j - n1 < n2) W2b[j - n1] = (bf16)W2[j - n1];
    }
}

__global__ void deg_hist(const void* __restrict__ ei, const float* __restrict__ ew,
                         float* __restrict__ deg, int* __restrict__ counts) {
    int e = blockIdx.x * blockDim.x + threadIdx.x;
    if (e >= N_EDGES) return;
    int is64 = detect64((const unsigned int*)ei);
    int d = load_idx(ei, N_EDGES + e, is64);
    atomicAdd(&deg[d], ew[e]);
    atomicAdd(&counts[d], 1);
}

// ---------- parallel scan, phase A: block-local scan + dis (fused) ----------
__global__ __launch_bounds__(256) void scan_partial(
    const int* __restrict__ counts, const float* __restrict__ deg,
    float* __restrict__ dis, int* __restrict__ row_ptr, int* __restrict__ partials)
{
    __shared__ int psum[256];
    int t = threadIdx.x;
    int i = blockIdx.x * 256 + t;
    if (i < N_NODES) {
        float dg = deg[i];
        dis[i] = (dg > 0.f) ? (1.0f / sqrtf(dg)) : 0.f;
    }
    int c = (i < N_NODES) ? counts[i] : 0;
    psum[t] = c;
    __syncthreads();
#pragma unroll
    for (int off = 1; off < 256; off <<= 1) {
        int v = (t >= off) ? psum[t - off] : 0;
        __syncthreads();
        psum[t] += v;
        __syncthreads();
    }
    if (i < N_NODES) row_ptr[i] = psum[t] - c;
    if (t == 255) partials[blockIdx.x] = psum[255];
}

// ---------- phase B: scan the 196 block totals ----------
__global__ __launch_bounds__(256) void scan_partials(int* __restrict__ partials,
                                                     int* __restrict__ row_ptr) {
    __shared__ int psum[256];
    int t = threadIdx.x;
    int p = (t < SCAN_NBLK) ? partials[t] : 0;
    psum[t] = p;
    __syncthreads();
#pragma unroll
    for (int off = 1; off < 256; off <<= 1) {
        int v = (t >= off) ? psum[t - off] : 0;
        __syncthreads();
        psum[t] += v;
        __syncthreads();
    }
    if (t < SCAN_NBLK) partials[t] = psum[t] - p;
    if (t == 255) row_ptr[N_NODES] = psum[255];
}

// ---------- phase C: add block offsets ----------
__global__ void scan_add(int* __restrict__ row_ptr, const int* __restrict__ partials) {
    int i = blockIdx.x * 256 + threadIdx.x;
    if (i < N_NODES) row_ptr[i] += partials[blockIdx.x];
}

// ---------- fill CSR with PACKED edges: int2{src, coef_bits} ----------
__global__ void fill_csr(const void* __restrict__ ei, const float* __restrict__ ew,
                         const float* __restrict__ dis, const int* __restrict__ row_ptr,
                         int* __restrict__ cursor, int2* __restrict__ edges) {
    int e = blockIdx.x * blockDim.x + threadIdx.x;
    if (e >= N_EDGES) return;
    int is64 = detect64((const unsigned int*)ei);
    int s = load_idx(ei, e, is64);
    int d = load_idx(ei, N_EDGES + e, is64);
    float coef = dis[s] * ew[e] * dis[d];
    int pos = row_ptr[d] + atomicAdd(&cursor[d], 1);
    edges[pos] = make_int2(s, __float_as_int(coef));
}

// ---------- gather aggregation, C=256: TWO nodes per wave (dual dep-chains) ----------
__global__ __launch_bounds__(256) void gather_agg_c256(
    const bf16* __restrict__ xb, const float* __restrict__ dis,
    const int* __restrict__ row_ptr, const int2* __restrict__ edges,
    bf16* __restrict__ agg)
{
    int wid = threadIdx.x >> 6;
    int lane = threadIdx.x & 63;
    int n0 = blockIdx.x * 8 + wid * 2;
    if (n0 >= N_NODES) return;
    int n1 = (n0 + 1 < N_NODES) ? n0 + 1 : n0;

    float s0 = dis[n0]; s0 *= s0;
    float s1 = dis[n1]; s1 *= s1;
    bf16x4 t0 = *(const bf16x4*)(xb + (size_t)n0 * IN_CH + lane * 4);
    bf16x4 t1 = *(const bf16x4*)(xb + (size_t)n1 * IN_CH + lane * 4);
    float a0[4], a1[4];
#pragma unroll
    for (int i = 0; i < 4; ++i) { a0[i] = s0 * (float)t0[i]; a1[i] = s1 * (float)t1[i]; }

    int b0 = row_ptr[n0], c0 = row_ptr[n0 + 1] - b0;
    int b1 = row_ptr[n1], c1 = row_ptr[n1 + 1] - b1;
    int cmin = c0 < c1 ? c0 : c1;
    int k = 0;
#pragma unroll 2
    for (; k < cmin; ++k) {                       // paired: 2 independent chains
        int2 ea = edges[b0 + k], eb = edges[b1 + k];
        float ca = __int_as_float(ea.y), cb = __int_as_float(eb.y);
        bf16x4 ra = *(const bf16x4*)(xb + (size_t)ea.x * IN_CH + lane * 4);
        bf16x4 rb = *(const bf16x4*)(xb + (size_t)eb.x * IN_CH + lane * 4);
#pragma unroll
        for (int i = 0; i < 4; ++i) { a0[i] += ca * (float)ra[i]; a1[i] += cb * (float)rb[i]; }
    }
    for (; k < c0; ++k) {
        int2 ea = edges[b0 + k];
        float ca = __int_as_float(ea.y);
        bf16x4 ra = *(const bf16x4*)(xb + (size_t)ea.x * IN_CH + lane * 4);
#pragma unroll
        for (int i = 0; i < 4; ++i) a0[i] += ca * (float)ra[i];
    }
    for (; k < c1; ++k) {
        int2 eb = edges[b1 + k];
        float cb = __int_as_float(eb.y);
        bf16x4 rb = *(const bf16x4*)(xb + (size_t)eb.x * IN_CH + lane * 4);
#pragma unroll
        for (int i = 0; i < 4; ++i) a1[i] += cb * (float)rb[i];
    }
    bf16x4 o0, o1;
#pragma unroll
    for (int i = 0; i < 4; ++i) { o0[i] = (bf16)a0[i]; o1[i] = (bf16)a1[i]; }
    *(bf16x4*)(agg + (size_t)n0 * IN_CH + lane * 4) = o0;
    *(bf16x4*)(agg + (size_t)n1 * IN_CH + lane * 4) = o1;
}

// ---------- gather aggregation, C=512: TWO nodes per wave ----------
__global__ __launch_bounds__(256) void gather_agg_c512(
    const bf16* __restrict__ p, const float* __restrict__ dis,
    const int* __restrict__ row_ptr, const int2* __restrict__ edges,
    bf16* __restrict__ agg)
{
    int wid = threadIdx.x >> 6;
    int lane = threadIdx.x & 63;
    int n0 = blockIdx.x * 8 + wid * 2;
    if (n0 >= N_NODES) return;
    int n1 = (n0 + 1 < N_NODES) ? n0 + 1 : n0;

    float s0 = dis[n0]; s0 *= s0;
    float s1 = dis[n1]; s1 *= s1;
    bf16x8 t0 = *(const bf16x8*)(p + (size_t)n0 * HID + lane * 8);
    bf16x8 t1 = *(const bf16x8*)(p + (size_t)n1 * HID + lane * 8);
    float a0[8], a1[8];
#pragma unroll
    for (int i = 0; i < 8; ++i) { a0[i] = s0 * (float)t0[i]; a1[i] = s1 * (float)t1[i]; }

    int b0 = row_ptr[n0], c0 = row_ptr[n0 + 1] - b0;
    int b1 = row_ptr[n1], c1 = row_ptr[n1 + 1] - b1;
    int cmin = c0 < c1 ? c0 : c1;
    int k = 0;
#pragma unroll 2
    for (; k < cmin; ++k) {                       // paired: 2 independent chains
        int2 ea = edges[b0 + k], eb = edges[b1 + k];
        float ca = __int_as_float(ea.y), cb = __int_as_float(eb.y);
        bf16x8 ra = *(const bf16x8*)(p + (size_t)ea.x * HID + lane * 8);
        bf16x8 rb = *(const bf16x8*)(p + (size_t)eb.x * HID + lane * 8);
#pragma unroll
        for (int i = 0; i < 8; ++i) { a0[i] += ca * (float)ra[i]; a1[i] += cb * (float)rb[i]; }
    }
    for (; k < c0; ++k) {
        int2 ea = edges[b0 + k];
        float ca = __int_as_float(ea.y);
        bf16x8 ra = *(const bf16x8*)(p + (size_t)ea.x * HID + lane * 8);
#pragma unroll
        for (int i = 0; i < 8; ++i) a0[i] += ca * (float)ra[i];
    }
    for (; k < c1; ++k) {
        int2 eb = edges[b1 + k];
        float cb = __int_as_float(eb.y);
        bf16x8 rb = *(const bf16x8*)(p + (size_t)eb.x * HID + lane * 8);
#pragma unroll
        for (int i = 0; i < 8; ++i) a1[i] += cb * (float)rb[i];
    }
    bf16x8 o0, o1;
#pragma unroll
    for (int i = 0; i < 8; ++i) { o0[i] = (bf16)a0[i]; o1[i] = (bf16)a1[i]; }
    *(bf16x8*)(agg + (size_t)n0 * HID + lane * 8) = o0;
    *(bf16x8*)(agg + (size_t)n1 * HID + lane * 8) = o1;
}

// ---------- MFMA bf16 GEMM: out[n,512] = X[n,K] @ Wt[512,K]^T + bias ----------
// 256x128 tile, 8 waves, BK=32 dbuf with counted vmcnt(3), T1 XCD swizzle.
template <int K, bool PRELU, bool OUT_BF16>
__global__ __launch_bounds__(512) void gemm_mfma(
    const bf16* __restrict__ X, const bf16* __restrict__ Wt,
    const float* __restrict__ bias, const float* __restrict__ prelu_a,
    void* __restrict__ outv, int n)
{
    constexpr int T = K / 32;
    __shared__ __align__(16) bf16 As[2][256 * 32];
    __shared__ __align__(16) bf16 Bs[2][128 * 32];
    const int tid = threadIdx.x;
    const int lane = tid & 63;
    const int wid = tid >> 6;              // 0..7
    const int wr = wid >> 1;               // 0..3 -> 64-row strip
    const int wc = wid & 1;                // 0..1 -> 64-col strip

    // bijective chunked XCD swizzle (T1); nwg = 784, 784%8==0
    const int nwg = gridDim.x;
    const int q = nwg >> 3, r8 = nwg & 7;
    int xcd = blockIdx.x & 7, slot = blockIdx.x >> 3;
    int newid = (xcd < r8 ? xcd * (q + 1) : r8 * (q + 1) + (xcd - r8) * q) + slot;
    const int row0 = (newid >> 2) * 256;   // col-fast: 4 col-blocks adjacent
    const int col0 = (newid & 3) * 128;

    auto STAGE = [&](int buf, int t) {
#pragma unroll
        for (int h = 0; h < 2; ++h) {
            int ss = tid + h * 512;          // 0..1023
            int r = ss >> 2;                 // 0..255
            int c = (ss & 3) ^ (r & 3);      // inverse-permuted source seg
            int ra = row0 + r; if (ra >= n) ra = n - 1;
            load_lds16(X + (size_t)ra * K + t * 32 + c * 8, &As[buf][ss * 8]);
        }
        {
            int r = tid >> 2;                // 0..127
            int c = (tid & 3) ^ (r & 3);
            load_lds16(Wt + (size_t)(col0 + r) * K + t * 32 + c * 8, &Bs[buf][tid * 8]);
        }
    };

    f32x4 acc[4][4] = {};
    STAGE(0, 0);

#pragma unroll
    for (int t = 0; t < T; ++t) {
        if (t + 1 < T) {
            STAGE((t + 1) & 1, t + 1);               // prefetch next tile
            asm volatile("s_waitcnt vmcnt(3)");      // wait only CURRENT tile's 3 loads
        } else {
            asm volatile("s_waitcnt vmcnt(0)");      // last tile: drain
        }
        __builtin_amdgcn_s_barrier();
        __builtin_amdgcn_sched_barrier(0);           // rule #18: pin reads after barrier

        const bf16* Ab = As[t & 1];
        const bf16* Bb = Bs[t & 1];
        bf16x8 af[4], bfr[4];
#pragma unroll
        for (int m = 0; m < 4; ++m) {
            int r = wr * 64 + m * 16 + (lane & 15);          // 0..255
            int seg = r * 4 + ((lane >> 4) ^ (r & 3));
            af[m] = *(const bf16x8*)&Ab[seg * 8];
        }
#pragma unroll
        for (int nn = 0; nn < 4; ++nn) {
            int r = wc * 64 + nn * 16 + (lane & 15);         // 0..127
            int seg = r * 4 + ((lane >> 4) ^ (r & 3));
            bfr[nn] = *(const bf16x8*)&Bb[seg * 8];
        }
#pragma unroll
        for (int m = 0; m < 4; ++m)
#pragma unroll
            for (int nn = 0; nn < 4; ++nn)
                acc[m][nn] = __builtin_amdgcn_mfma_f32_16x16x32_bf16(
                    af[m], bfr[nn], acc[m][nn], 0, 0, 0);

        __builtin_amdgcn_sched_barrier(0);           // keep reads before the release barrier
        __builtin_amdgcn_s_barrier();                // all reads done -> next iter may restage
    }

    const float ap = PRELU ? *prelu_a : 0.f;
#pragma unroll
    for (int m = 0; m < 4; ++m) {
        int gr_base = row0 + wr * 64 + m * 16 + (lane >> 4) * 4;
#pragma unroll
        for (int nn = 0; nn < 4; ++nn) {
            int gc = col0 + wc * 64 + nn * 16 + (lane & 15);
            float bv = bias[gc];
#pragma unroll
            for (int j = 0; j < 4; ++j) {
                int gr = gr_base + j;
                if (gr < n) {
                    float v = acc[m][nn][j] + bv;
                    if (PRELU) v = (v >= 0.f) ? v : ap * v;
                    if (OUT_BF16) ((bf16*)outv)[(size_t)gr * HID + gc] = (bf16)v;
                    else         ((float*)outv)[(size_t)gr * HID + gc] = v;
                }
            }
        }
    }
}

extern "C" void kernel_launch(void* const* d_in, const int* in_sizes, int n_in,
                              void* d_out, int out_size, void* d_ws, size_t ws_size,
                              hipStream_t stream) {
    const float* x  = (const float*)d_in[0];
    const void*  ei = d_in[1];
    const float* ew = (const float*)d_in[2];
    const float* W1 = (const float*)d_in[3];
    const float* b1 = (const float*)d_in[4];
    const float* W2 = (const float*)d_in[5];
    const float* b2 = (const float*)d_in[6];
    const float* pa = (const float*)d_in[7];

    char* base = (char*)d_ws;
    bf16*  aggb     = (bf16*)base;                          // 51.2 MB
    bf16*  xb       = (bf16*)(base + (size_t)N_NODES * HID * 2);   // 25.6 MB
    bf16*  W1b      = xb + (size_t)N_NODES * IN_CH;
    bf16*  W2b      = W1b + HID * IN_CH;
    float* deg      = (float*)(W2b + HID * HID);
    float* dis      = deg + N_NODES;
    int*   counts   = (int*)(dis + N_NODES);
    int*   cursor   = counts + N_NODES;
    int*   row_ptr  = cursor + N_NODES;                     // N_NODES+1
    int2*  edges    = (int2*)(row_ptr + N_NODES + 2);       // N_EDGES (8B each), aligned
    int*   partials = (int*)(edges + N_EDGES);              // SCAN_NBLK

    bf16* p_bf = (bf16*)d_out;   // layer-1 bf16 output lives in d_out, consumed before GEMM2 writes f32

    const int NB = SCAN_NBLK;
    const int EB = (N_EDGES + 255) / 256;
    const int GEMM_NWG = (HID / 128) * ((N_NODES + 255) / 256);   // 4 * 196 = 784

    // ----- prep: node-array init + all dtype conversions (one launch) -----
    {
        int total = N_NODES * IN_CH / 8 + HID * IN_CH + HID * HID;
        prep_kernel<<<(total + 255) / 256, 256, 0, stream>>>(
            deg, counts, cursor, x, xb, W1, W1b, HID * IN_CH, W2, W2b, HID * HID);
    }

    // ----- CSR build (once, reused by both layers) -----
    deg_hist<<<EB, 256, 0, stream>>>(ei, ew, deg, counts);
    scan_partial<<<NB, 256, 0, stream>>>(counts, deg, dis, row_ptr, partials);
    scan_partials<<<1, 256, 0, stream>>>(partials, row_ptr);
    scan_add<<<NB, 256, 0, stream>>>(row_ptr, partials);
    fill_csr<<<EB, 256, 0, stream>>>(ei, ew, dis, row_ptr, cursor, edges);

    // ----- layer 1: gather bf16 x -> GEMM + bias + PReLU -> bf16 p (in d_out) -----
    gather_agg_c256<<<(N_NODES + 7) / 8, 256, 0, stream>>>(xb, dis, row_ptr, edges, aggb);
    gemm_mfma<IN_CH, true, true><<<GEMM_NWG, 512, 0, stream>>>(
        aggb, W1b, b1, pa, p_bf, N_NODES);

    // ----- layer 2: gather bf16 p -> GEMM + bias -> f32 d_out -----
    gather_agg_c512<<<(N_NODES + 7) / 8, 256, 0, stream>>>(p_bf, dis, row_ptr, edges, aggb);
    gemm_mfma<HID, false, false><<<GEMM_NWG, 512, 0, stream>>>(
        aggb, W2b, b2, pa, (float*)d_out, N_NODES);
}